// Round 4
// baseline (270.623 us; speedup 1.0000x reference)
//
#include <hip/hip_runtime.h>
#include <hip/hip_fp16.h>

// Problem constants: B=2, T=32, H=64, W=64, C=64, KT=5, K=7. Circular dims pow2 -> & masks.
#define PLANE (64 * 64 * 64)          // H*W*C elements per (b,t)
#define NELEM 16777216                // B*T*H*W*C

typedef _Float16 f16x8 __attribute__((ext_vector_type(8)));
typedef _Float16 h2v  __attribute__((ext_vector_type(2)));
typedef float f32x4 __attribute__((ext_vector_type(4)));

// ---------------- fused dual projection GEMM (MFMA f16) ----------------
__global__ __launch_bounds__(256) void proj2_kernel(
    const float* __restrict__ x,
    const float* __restrict__ wg, const float* __restrict__ bg,
    const float* __restrict__ wh, const float* __restrict__ bh,
    _Float16* __restrict__ pg, _Float16* __restrict__ ph)
{
    __shared__ __align__(16) _Float16 sX[128 * 64];     // rows, 16B-chunk XOR swizzle
    __shared__ __align__(16) _Float16 sWT[2][64 * 64];  // [mat][d][c] transposed, swizzled
    const int tid = threadIdx.x;
    const long long row0 = (long long)blockIdx.x * 128;

    #pragma unroll
    for (int kci = 0; kci < 4; ++kci) {
        const int chunk = tid + kci * 256;
        const int r = chunk >> 3, q = chunk & 7;
        const float* gp = x + (row0 + r) * 64 + q * 8;
        const float4 v0 = *reinterpret_cast<const float4*>(gp);
        const float4 v1 = *reinterpret_cast<const float4*>(gp + 4);
        f16x8 hv;
        hv[0] = (_Float16)v0.x; hv[1] = (_Float16)v0.y; hv[2] = (_Float16)v0.z; hv[3] = (_Float16)v0.w;
        hv[4] = (_Float16)v1.x; hv[5] = (_Float16)v1.y; hv[6] = (_Float16)v1.z; hv[7] = (_Float16)v1.w;
        *reinterpret_cast<f16x8*>(&sX[r * 64 + ((q ^ (r & 7)) * 8)]) = hv;
    }
    {
        const int d = tid & 63;
        const int cb = (tid >> 6) * 16;
        #pragma unroll
        for (int i = 0; i < 16; ++i) {
            const int c = cb + i;
            const int off = d * 64 + (((c >> 3) ^ (d & 7)) * 8) + (c & 7);
            sWT[0][off] = (_Float16)wg[c * 64 + d];
            sWT[1][off] = (_Float16)wh[c * 64 + d];
        }
    }
    __syncthreads();

    const int wv = tid >> 6, lm = tid & 15, lg = (tid & 63) >> 4;
    f16x8 bf[2][4][2];                       // [mat][ntile][kstep]
    #pragma unroll
    for (int nt = 0; nt < 4; ++nt) {
        const int d = nt * 16 + lm;
        #pragma unroll
        for (int s = 0; s < 2; ++s) {
            const int off = d * 64 + (((s * 4 + lg) ^ (d & 7)) * 8);
            bf[0][nt][s] = *reinterpret_cast<const f16x8*>(&sWT[0][off]);
            bf[1][nt][s] = *reinterpret_cast<const f16x8*>(&sWT[1][off]);
        }
    }
    f32x4 acc[2][2][4];                      // [mat][mtile][ntile]
    #pragma unroll
    for (int m = 0; m < 2; ++m)
        #pragma unroll
        for (int mt = 0; mt < 2; ++mt)
            #pragma unroll
            for (int nt = 0; nt < 4; ++nt)
                acc[m][mt][nt] = (f32x4){0.f, 0.f, 0.f, 0.f};

    #pragma unroll
    for (int mt = 0; mt < 2; ++mt) {
        const int r = wv * 32 + mt * 16 + lm;
        const f16x8 a0 = *reinterpret_cast<const f16x8*>(&sX[r * 64 + ((lg ^ (r & 7)) * 8)]);
        const f16x8 a1 = *reinterpret_cast<const f16x8*>(&sX[r * 64 + (((4 + lg) ^ (r & 7)) * 8)]);
        #pragma unroll
        for (int nt = 0; nt < 4; ++nt) {
            acc[0][mt][nt] = __builtin_amdgcn_mfma_f32_16x16x32_f16(a0, bf[0][nt][0], acc[0][mt][nt], 0, 0, 0);
            acc[0][mt][nt] = __builtin_amdgcn_mfma_f32_16x16x32_f16(a1, bf[0][nt][1], acc[0][mt][nt], 0, 0, 0);
            acc[1][mt][nt] = __builtin_amdgcn_mfma_f32_16x16x32_f16(a0, bf[1][nt][0], acc[1][mt][nt], 0, 0, 0);
            acc[1][mt][nt] = __builtin_amdgcn_mfma_f32_16x16x32_f16(a1, bf[1][nt][1], acc[1][mt][nt], 0, 0, 0);
        }
    }
    #pragma unroll
    for (int nt = 0; nt < 4; ++nt) {
        const int col = nt * 16 + lm;
        const float bgv = bg[col], bhv = bh[col];
        #pragma unroll
        for (int mt = 0; mt < 2; ++mt) {
            const long long rb = row0 + wv * 32 + mt * 16 + lg * 4;
            #pragma unroll
            for (int i = 0; i < 4; ++i) {
                pg[(rb + i) * 64 + col] = (_Float16)(acc[0][mt][nt][i] + bgv);
                ph[(rb + i) * 64 + col] = (_Float16)(acc[1][mt][nt][i] + bhv);
            }
        }
    }
}

// ---------------- depthwise circular 3D conv, wave-block pk-f16 ----------------
// Block = 1 wave (64 thr): 16h x 16w spatial x 8 channels (4 half2 pairs).
// Thread (p=lane&3, iq=(lane>>2)&3, wq=lane>>4) computes 4 ih x 4 w for its pair.
// sIn[p][ii][jj]: pair stride 552 (552%32==8 -> even b128 bank footprint), row stride 24.
// sK[p][(kt*7+kh)*8+kw]: pair stride 296 (%32==8 -> distinct 8-stride starts, broadcast-free).
__global__ __launch_bounds__(64) void conv3d_kernel(
    const _Float16* __restrict__ in, const float* __restrict__ kern, _Float16* __restrict__ out)
{
    __shared__ __align__(16) uint sIn[4 * 552];     // 8832 B
    __shared__ __align__(16) uint sK[4 * 296];      // 4736 B

    int bid = (int)blockIdx.x;
    int l = (bid & 7) * 1024 + (bid >> 3);          // XCD swizzle: 1024 logical blocks/XCD
    const int cg = l & 7;   l >>= 3;
    const int wb = l & 3;   l >>= 2;
    const int hb = l & 3;   l >>= 2;
    const int t  = l & 31;  l >>= 5;
    const int b  = l;
    const int h0 = hb * 16, w0 = wb * 16, c0 = cg * 8;
    const int lane = threadIdx.x;

    // stage taps: 4 pairs x 245
    for (int i = lane; i < 980; i += 64) {
        const int p = i / 245, tap = i - p * 245;
        const int kt = tap / 49, r2 = tap - kt * 49;
        const int kh = r2 / 7, kw = r2 - kh * 7;
        h2v hv;
        hv[0] = (_Float16)kern[(c0 + 2 * p) * 245 + tap];
        hv[1] = (_Float16)kern[(c0 + 2 * p + 1) * 245 + tap];
        sK[p * 296 + (kt * 7 + kh) * 8 + kw] = __builtin_bit_cast(uint, hv);
    }

    // per-thread staging addresses: 8 chunks of 8ch (uint4) over the 22x22 halo
    int soff[8], loff[8];
    #pragma unroll
    for (int it = 0; it < 8; ++it) {
        int c = it * 64 + lane;
        int pos = c > 483 ? 483 : c;
        const int ii = pos / 22, jj = pos - ii * 22;
        const int gh = (h0 - 3 + ii) & 63, gw = (w0 - 3 + jj) & 63;
        soff[it] = (gh * 64 + gw) * 64 + c0;
        loff[it] = ii * 24 + jj;
    }

    const int p  = lane & 3;
    const int iq = (lane >> 2) & 3;
    const int wq = lane >> 4;
    const int rowbase = p * 552 + wq * 4;
    const int kbase   = p * 296;

    const _Float16* base = in + (long long)b * 32 * PLANE;

    uint4 ld[8];
    {
        const _Float16* pl = base + (long long)((t + 2) & 31) * PLANE;
        #pragma unroll
        for (int it = 0; it < 8; ++it)
            ld[it] = *reinterpret_cast<const uint4*>(pl + soff[it]);
    }

    h2v tot[4][4];
    #pragma unroll
    for (int o = 0; o < 4; ++o)
        #pragma unroll
        for (int j = 0; j < 4; ++j) tot[o][j] = (h2v)(_Float16)0;

    for (int kt = 0; kt < 5; ++kt) {
        // write staged plane (wave-synchronous; DS in-order, no barrier)
        #pragma unroll
        for (int it = 0; it < 8; ++it) {
            const int a = loff[it];
            sIn[a]           = ld[it].x;
            sIn[a + 552]     = ld[it].y;
            sIn[a + 2 * 552] = ld[it].z;
            sIn[a + 3 * 552] = ld[it].w;
        }
        // prefetch next plane while computing this one
        if (kt < 4) {
            const _Float16* pl = base + (long long)((t - kt + 1) & 31) * PLANE;
            #pragma unroll
            for (int it = 0; it < 8; ++it)
                ld[it] = *reinterpret_cast<const uint4*>(pl + soff[it]);
        }

        h2v acc[4][4];
        #pragma unroll
        for (int o = 0; o < 4; ++o)
            #pragma unroll
            for (int j = 0; j < 4; ++j) acc[o][j] = (h2v)(_Float16)0;

        h2v kv[4][8];                       // tap ring: kh -> slot kh&3
        const int ktap = kbase + kt * 56;

        #pragma unroll
        for (int rr = 0; rr < 10; ++rr) {
            if (rr <= 6) {                  // load taps for kh = 6-rr (first use at this rr)
                const int kh = 6 - rr;
                const uint4 k0 = *reinterpret_cast<const uint4*>(&sK[ktap + kh * 8]);
                const uint4 k1 = *reinterpret_cast<const uint4*>(&sK[ktap + kh * 8 + 4]);
                kv[kh & 3][0] = __builtin_bit_cast(h2v, k0.x);
                kv[kh & 3][1] = __builtin_bit_cast(h2v, k0.y);
                kv[kh & 3][2] = __builtin_bit_cast(h2v, k0.z);
                kv[kh & 3][3] = __builtin_bit_cast(h2v, k0.w);
                kv[kh & 3][4] = __builtin_bit_cast(h2v, k1.x);
                kv[kh & 3][5] = __builtin_bit_cast(h2v, k1.y);
                kv[kh & 3][6] = __builtin_bit_cast(h2v, k1.z);
                kv[kh & 3][7] = __builtin_bit_cast(h2v, k1.w);
            }
            // load input row ii = 4*iq + rr, cols wq*4 .. wq*4+11 (10 used)
            const uint* rp = &sIn[rowbase + (4 * iq + rr) * 24];
            const uint4 r0 = *reinterpret_cast<const uint4*>(rp);
            const uint4 r1 = *reinterpret_cast<const uint4*>(rp + 4);
            const uint4 r2 = *reinterpret_cast<const uint4*>(rp + 8);
            h2v row[12];
            row[0] = __builtin_bit_cast(h2v, r0.x); row[1] = __builtin_bit_cast(h2v, r0.y);
            row[2] = __builtin_bit_cast(h2v, r0.z); row[3] = __builtin_bit_cast(h2v, r0.w);
            row[4] = __builtin_bit_cast(h2v, r1.x); row[5] = __builtin_bit_cast(h2v, r1.y);
            row[6] = __builtin_bit_cast(h2v, r1.z); row[7] = __builtin_bit_cast(h2v, r1.w);
            row[8] = __builtin_bit_cast(h2v, r2.x); row[9] = __builtin_bit_cast(h2v, r2.y);
            row[10] = __builtin_bit_cast(h2v, r2.z); row[11] = __builtin_bit_cast(h2v, r2.w);

            #pragma unroll
            for (int o = 0; o < 4; ++o) {
                const int kh = o + 6 - rr;
                if (kh < 0 || kh > 6) continue;
                #pragma unroll
                for (int kw = 0; kw < 7; ++kw)
                    #pragma unroll
                    for (int j = 0; j < 4; ++j)
                        acc[o][j] = __builtin_elementwise_fma(kv[kh & 3][kw], row[j + 6 - kw], acc[o][j]);
            }
        }
        #pragma unroll
        for (int o = 0; o < 4; ++o)
            #pragma unroll
            for (int j = 0; j < 4; ++j) tot[o][j] += acc[o][j];
    }

    _Float16* ob = out + (long long)b * 32 * PLANE + (long long)t * PLANE;
    #pragma unroll
    for (int o = 0; o < 4; ++o) {
        #pragma unroll
        for (int j = 0; j < 4; ++j) {
            _Float16* dst = ob + (((h0 + 4 * iq + o) * 64 + w0 + wq * 4 + j) * 64 + c0 + 2 * p);
            *reinterpret_cast<uint*>(dst) = __builtin_bit_cast(uint, tot[o][j]);
        }
    }
}

// ---------------- minGRU scan over T (f32 math, f16 I/O) ----------------
__global__ __launch_bounds__(256) void scan_kernel(
    const __half2* __restrict__ gs, const __half2* __restrict__ hs, __half2* __restrict__ hout)
{
    const int tid = blockIdx.x * 256 + threadIdx.x;    // 0..262143 half2 lanes
    const int b = tid >> 17;
    const int q = tid & 131071;
    const long long bb = (long long)b * 32 * 131072 + q;
    float h0 = 0.f, h1 = 0.f;
    for (int t = 0; t < 32; ++t) {
        const long long a = bb + (long long)t * 131072;
        const float2 g  = __half22float2(gs[a]);
        const float2 hv = __half22float2(hs[a]);
        const float z0 = 1.f / (1.f + __expf(-g.x));
        const float z1 = 1.f / (1.f + __expf(-g.y));
        h0 = fmaf(1.f - z0, h0, z0 * fmaf(hv.x, hv.x, 1e-6f));
        h1 = fmaf(1.f - z1, h1, z1 * fmaf(hv.y, hv.y, 1e-6f));
        hout[a] = __floats2half2_rn(h0, h1);
    }
}

// ---------------- output GEMM (MFMA f16, f32 out) ----------------
__global__ __launch_bounds__(256) void outgemm_kernel(
    const _Float16* __restrict__ hin, const float* __restrict__ w,
    const float* __restrict__ bias, float* __restrict__ out)
{
    __shared__ __align__(16) _Float16 sX[128 * 64];
    __shared__ __align__(16) _Float16 sWT[64 * 64];
    const int tid = threadIdx.x;
    const long long row0 = (long long)blockIdx.x * 128;

    #pragma unroll
    for (int kci = 0; kci < 4; ++kci) {
        const int chunk = tid + kci * 256;
        const int r = chunk >> 3, q = chunk & 7;
        const f16x8 hv = *reinterpret_cast<const f16x8*>(hin + (row0 + r) * 64 + q * 8);
        *reinterpret_cast<f16x8*>(&sX[r * 64 + ((q ^ (r & 7)) * 8)]) = hv;
    }
    {
        const int d = tid & 63;
        const int cb = (tid >> 6) * 16;
        #pragma unroll
        for (int i = 0; i < 16; ++i) {
            const int c = cb + i;
            sWT[d * 64 + (((c >> 3) ^ (d & 7)) * 8) + (c & 7)] = (_Float16)w[c * 64 + d];
        }
    }
    __syncthreads();

    const int wv = tid >> 6, lm = tid & 15, lg = (tid & 63) >> 4;
    f16x8 bf[4][2];
    #pragma unroll
    for (int nt = 0; nt < 4; ++nt) {
        const int d = nt * 16 + lm;
        #pragma unroll
        for (int s = 0; s < 2; ++s)
            bf[nt][s] = *reinterpret_cast<const f16x8*>(&sWT[d * 64 + (((s * 4 + lg) ^ (d & 7)) * 8)]);
    }
    f32x4 acc[2][4];
    #pragma unroll
    for (int mt = 0; mt < 2; ++mt)
        #pragma unroll
        for (int nt = 0; nt < 4; ++nt)
            acc[mt][nt] = (f32x4){0.f, 0.f, 0.f, 0.f};

    #pragma unroll
    for (int mt = 0; mt < 2; ++mt) {
        const int r = wv * 32 + mt * 16 + lm;
        const f16x8 a0 = *reinterpret_cast<const f16x8*>(&sX[r * 64 + ((lg ^ (r & 7)) * 8)]);
        const f16x8 a1 = *reinterpret_cast<const f16x8*>(&sX[r * 64 + (((4 + lg) ^ (r & 7)) * 8)]);
        #pragma unroll
        for (int nt = 0; nt < 4; ++nt) {
            acc[mt][nt] = __builtin_amdgcn_mfma_f32_16x16x32_f16(a0, bf[nt][0], acc[mt][nt], 0, 0, 0);
            acc[mt][nt] = __builtin_amdgcn_mfma_f32_16x16x32_f16(a1, bf[nt][1], acc[mt][nt], 0, 0, 0);
        }
    }
    #pragma unroll
    for (int nt = 0; nt < 4; ++nt) {
        const int col = nt * 16 + lm;
        const float bv = bias[col];
        #pragma unroll
        for (int mt = 0; mt < 2; ++mt) {
            const long long rb = row0 + wv * 32 + mt * 16 + lg * 4;
            #pragma unroll
            for (int i = 0; i < 4; ++i)
                out[(rb + i) * 64 + col] = acc[mt][nt][i] + bv;
        }
    }
}

extern "C" void kernel_launch(void* const* d_in, const int* in_sizes, int n_in,
                              void* d_out, int out_size, void* d_ws, size_t ws_size,
                              hipStream_t stream)
{
    const float* x  = (const float*)d_in[0];
    const float* gw = (const float*)d_in[1];
    const float* gb = (const float*)d_in[2];
    const float* hw = (const float*)d_in[3];
    const float* hb = (const float*)d_in[4];
    const float* gk = (const float*)d_in[5];
    const float* hk = (const float*)d_in[6];
    const float* ow = (const float*)d_in[7];
    const float* ob = (const float*)d_in[8];

    _Float16* W1 = (_Float16*)d_ws;          // 33.5 MB each
    _Float16* W2 = W1 + NELEM;
    _Float16* W3 = W2 + NELEM;

    // 1) proj: x -> W1 (gate_proj f16), W2 (hidden_proj f16)
    proj2_kernel<<<2048, 256, 0, stream>>>(x, gw, gb, hw, hb, W1, W2);
    // 2) gate conv: W1 -> W3 (gate_spatial)
    conv3d_kernel<<<8192, 64, 0, stream>>>(W1, gk, W3);
    // 3) hidden conv: W2 -> W1 (hidden_spatial)
    conv3d_kernel<<<8192, 64, 0, stream>>>(W2, hk, W1);
    // 4) scan: (W3, W1) -> W2
    scan_kernel<<<1024, 256, 0, stream>>>((const __half2*)W3, (const __half2*)W1, (__half2*)W2);
    // 5) out GEMM: W2 -> d_out (f32)
    outgemm_kernel<<<2048, 256, 0, stream>>>(W2, ow, ob, (float*)d_out);
}

// Round 5
// 264.750 us; speedup vs baseline: 1.0222x; 1.0222x over previous
//
#include <hip/hip_runtime.h>
#include <hip/hip_fp16.h>

// Problem constants: B=2, T=32, H=64, W=64, C=64, KT=5, K=7. Circular dims pow2 -> & masks.
#define PLANE (64 * 64 * 64)          // H*W*C elements per (b,t)
#define NELEM 16777216                // B*T*H*W*C

typedef _Float16 f16x8 __attribute__((ext_vector_type(8)));
typedef _Float16 h2v  __attribute__((ext_vector_type(2)));
typedef float f32x4 __attribute__((ext_vector_type(4)));

// Guaranteed-packed f16 math (VOP3P). Register-only asm: deps tracked via
// constraints, so the scheduler can still move/interleave these freely.
static __device__ __forceinline__ void pk_fma(uint& d, uint a, uint b) {
    asm("v_pk_fma_f16 %0, %1, %2, %0" : "+v"(d) : "v"(a), "v"(b));
}
static __device__ __forceinline__ void pk_add(uint& d, uint a) {
    asm("v_pk_add_f16 %0, %1, %0" : "+v"(d) : "v"(a));
}

// ---------------- fused dual projection GEMM (MFMA f16) ----------------
__global__ __launch_bounds__(256) void proj2_kernel(
    const float* __restrict__ x,
    const float* __restrict__ wg, const float* __restrict__ bg,
    const float* __restrict__ wh, const float* __restrict__ bh,
    _Float16* __restrict__ pg, _Float16* __restrict__ ph)
{
    __shared__ __align__(16) _Float16 sX[128 * 64];     // rows, 16B-chunk XOR swizzle
    __shared__ __align__(16) _Float16 sWT[2][64 * 64];  // [mat][d][c] transposed, swizzled
    const int tid = threadIdx.x;
    const long long row0 = (long long)blockIdx.x * 128;

    #pragma unroll
    for (int kci = 0; kci < 4; ++kci) {
        const int chunk = tid + kci * 256;
        const int r = chunk >> 3, q = chunk & 7;
        const float* gp = x + (row0 + r) * 64 + q * 8;
        const float4 v0 = *reinterpret_cast<const float4*>(gp);
        const float4 v1 = *reinterpret_cast<const float4*>(gp + 4);
        f16x8 hv;
        hv[0] = (_Float16)v0.x; hv[1] = (_Float16)v0.y; hv[2] = (_Float16)v0.z; hv[3] = (_Float16)v0.w;
        hv[4] = (_Float16)v1.x; hv[5] = (_Float16)v1.y; hv[6] = (_Float16)v1.z; hv[7] = (_Float16)v1.w;
        *reinterpret_cast<f16x8*>(&sX[r * 64 + ((q ^ (r & 7)) * 8)]) = hv;
    }
    {
        const int d = tid & 63;
        const int cb = (tid >> 6) * 16;
        #pragma unroll
        for (int i = 0; i < 16; ++i) {
            const int c = cb + i;
            const int off = d * 64 + (((c >> 3) ^ (d & 7)) * 8) + (c & 7);
            sWT[0][off] = (_Float16)wg[c * 64 + d];
            sWT[1][off] = (_Float16)wh[c * 64 + d];
        }
    }
    __syncthreads();

    const int wv = tid >> 6, lm = tid & 15, lg = (tid & 63) >> 4;
    f16x8 bf[2][4][2];                       // [mat][ntile][kstep]
    #pragma unroll
    for (int nt = 0; nt < 4; ++nt) {
        const int d = nt * 16 + lm;
        #pragma unroll
        for (int s = 0; s < 2; ++s) {
            const int off = d * 64 + (((s * 4 + lg) ^ (d & 7)) * 8);
            bf[0][nt][s] = *reinterpret_cast<const f16x8*>(&sWT[0][off]);
            bf[1][nt][s] = *reinterpret_cast<const f16x8*>(&sWT[1][off]);
        }
    }
    f32x4 acc[2][2][4];                      // [mat][mtile][ntile]
    #pragma unroll
    for (int m = 0; m < 2; ++m)
        #pragma unroll
        for (int mt = 0; mt < 2; ++mt)
            #pragma unroll
            for (int nt = 0; nt < 4; ++nt)
                acc[m][mt][nt] = (f32x4){0.f, 0.f, 0.f, 0.f};

    #pragma unroll
    for (int mt = 0; mt < 2; ++mt) {
        const int r = wv * 32 + mt * 16 + lm;
        const f16x8 a0 = *reinterpret_cast<const f16x8*>(&sX[r * 64 + ((lg ^ (r & 7)) * 8)]);
        const f16x8 a1 = *reinterpret_cast<const f16x8*>(&sX[r * 64 + (((4 + lg) ^ (r & 7)) * 8)]);
        #pragma unroll
        for (int nt = 0; nt < 4; ++nt) {
            acc[0][mt][nt] = __builtin_amdgcn_mfma_f32_16x16x32_f16(a0, bf[0][nt][0], acc[0][mt][nt], 0, 0, 0);
            acc[0][mt][nt] = __builtin_amdgcn_mfma_f32_16x16x32_f16(a1, bf[0][nt][1], acc[0][mt][nt], 0, 0, 0);
            acc[1][mt][nt] = __builtin_amdgcn_mfma_f32_16x16x32_f16(a0, bf[1][nt][0], acc[1][mt][nt], 0, 0, 0);
            acc[1][mt][nt] = __builtin_amdgcn_mfma_f32_16x16x32_f16(a1, bf[1][nt][1], acc[1][mt][nt], 0, 0, 0);
        }
    }
    #pragma unroll
    for (int nt = 0; nt < 4; ++nt) {
        const int col = nt * 16 + lm;
        const float bgv = bg[col], bhv = bh[col];
        #pragma unroll
        for (int mt = 0; mt < 2; ++mt) {
            const long long rb = row0 + wv * 32 + mt * 16 + lg * 4;
            #pragma unroll
            for (int i = 0; i < 4; ++i) {
                pg[(rb + i) * 64 + col] = (_Float16)(acc[0][mt][nt][i] + bgv);
                ph[(rb + i) * 64 + col] = (_Float16)(acc[1][mt][nt][i] + bhv);
            }
        }
    }
}

// ---------------- depthwise circular 3D conv, dual-matrix, packed-asm f16 ----------------
// Block = 128 thr (2 waves). Each wave: 16h x 16w spatial x 8 channels (4 pairs),
// wave-private LDS slice, zero barriers. grid: [0,4096) gate, [4096,8192) hidden.
// sIn pair stride 552 (%32==8 -> balanced b128 banks), row stride 24.
// sK pair stride 296 (%32==8 -> distinct starts, broadcast-free).
__global__ __launch_bounds__(128, 3) void conv3d_dual_kernel(
    const _Float16* __restrict__ inG, const float* __restrict__ kG, _Float16* __restrict__ outG,
    const _Float16* __restrict__ inH, const float* __restrict__ kH, _Float16* __restrict__ outH)
{
    __shared__ __align__(16) uint sIn[2 * 2208];    // 17664 B
    __shared__ __align__(16) uint sK[2 * 1184];     //  9472 B

    const int bid = (int)blockIdx.x;
    const int mat = bid >> 12;
    const int local = bid & 4095;
    int l = (local & 7) * 512 + (local >> 3);       // XCD swizzle: 512 logical blocks/XCD
    const int cgp = l & 3;  l >>= 2;
    const int wb = l & 3;   l >>= 2;
    const int hb = l & 3;   l >>= 2;
    const int t  = l & 31;  l >>= 5;
    const int b  = l;
    const int wave = threadIdx.x >> 6;
    const int lane = threadIdx.x & 63;
    const int h0 = hb * 16, w0 = wb * 16, c0 = (cgp * 2 + wave) * 8;

    const _Float16* in = mat ? inH : inG;
    const float* kern  = mat ? kH  : kG;
    _Float16* out      = mat ? outH : outG;

    uint* mIn = sIn + wave * 2208;
    uint* mK  = sK  + wave * 1184;

    // stage taps: 4 pairs x 245 (wave-private slice)
    for (int i = lane; i < 980; i += 64) {
        const int p = i / 245, tap = i - p * 245;
        const int kt = tap / 49, r2 = tap - kt * 49;
        const int kh = r2 / 7, kw = r2 - kh * 7;
        h2v hv;
        hv[0] = (_Float16)kern[(c0 + 2 * p) * 245 + tap];
        hv[1] = (_Float16)kern[(c0 + 2 * p + 1) * 245 + tap];
        mK[p * 296 + (kt * 7 + kh) * 8 + kw] = __builtin_bit_cast(uint, hv);
    }

    // per-thread staging addresses: 8 chunks of 8ch (uint4) over the 22x22 halo
    int soff[8], loff[8];
    #pragma unroll
    for (int it = 0; it < 8; ++it) {
        int c = it * 64 + lane;
        int pos = c > 483 ? 483 : c;
        const int ii = pos / 22, jj = pos - ii * 22;
        const int gh = (h0 - 3 + ii) & 63, gw = (w0 - 3 + jj) & 63;
        soff[it] = (gh * 64 + gw) * 64 + c0;
        loff[it] = ii * 24 + jj;
    }

    const int p  = lane & 3;
    const int iq = (lane >> 2) & 3;
    const int wq = lane >> 4;
    const int rowbase = p * 552 + wq * 4;
    const int kbase   = p * 296;

    const _Float16* base = in + (long long)b * 32 * PLANE;

    uint4 ld[8];
    {
        const _Float16* pl = base + (long long)((t + 2) & 31) * PLANE;
        #pragma unroll
        for (int it = 0; it < 8; ++it)
            ld[it] = *reinterpret_cast<const uint4*>(pl + soff[it]);
    }

    uint tot[4][4];
    #pragma unroll
    for (int o = 0; o < 4; ++o)
        #pragma unroll
        for (int j = 0; j < 4; ++j) tot[o][j] = 0u;

    #pragma unroll 1
    for (int kt = 0; kt < 5; ++kt) {
        // write staged plane (wave-synchronous; DS in-order, no barrier)
        #pragma unroll
        for (int it = 0; it < 8; ++it) {
            const int a = loff[it];
            mIn[a]           = ld[it].x;
            mIn[a + 552]     = ld[it].y;
            mIn[a + 2 * 552] = ld[it].z;
            mIn[a + 3 * 552] = ld[it].w;
        }
        // prefetch next plane while computing this one
        if (kt < 4) {
            const _Float16* pl = base + (long long)((t - kt + 1) & 31) * PLANE;
            #pragma unroll
            for (int it = 0; it < 8; ++it)
                ld[it] = *reinterpret_cast<const uint4*>(pl + soff[it]);
        }

        uint acc[4][4];
        #pragma unroll
        for (int o = 0; o < 4; ++o)
            #pragma unroll
            for (int j = 0; j < 4; ++j) acc[o][j] = 0u;

        uint kv[4][8];                       // tap ring: kh -> slot kh&3
        const int ktap = kbase + kt * 56;

        #pragma unroll
        for (int rr = 0; rr < 10; ++rr) {
            if (rr <= 6) {                  // load taps for kh = 6-rr (first use at this rr)
                const int kh = 6 - rr;
                const uint4 k0 = *reinterpret_cast<const uint4*>(&mK[ktap + kh * 8]);
                const uint4 k1 = *reinterpret_cast<const uint4*>(&mK[ktap + kh * 8 + 4]);
                kv[kh & 3][0] = k0.x; kv[kh & 3][1] = k0.y;
                kv[kh & 3][2] = k0.z; kv[kh & 3][3] = k0.w;
                kv[kh & 3][4] = k1.x; kv[kh & 3][5] = k1.y;
                kv[kh & 3][6] = k1.z; kv[kh & 3][7] = k1.w;
            }
            // load input row ii = 4*iq + rr, cols wq*4 .. wq*4+11 (10 used)
            const uint* rp = &mIn[rowbase + (4 * iq + rr) * 24];
            const uint4 r0 = *reinterpret_cast<const uint4*>(rp);
            const uint4 r1 = *reinterpret_cast<const uint4*>(rp + 4);
            const uint4 r2 = *reinterpret_cast<const uint4*>(rp + 8);
            uint row[12];
            row[0] = r0.x; row[1] = r0.y; row[2]  = r0.z; row[3]  = r0.w;
            row[4] = r1.x; row[5] = r1.y; row[6]  = r1.z; row[7]  = r1.w;
            row[8] = r2.x; row[9] = r2.y; row[10] = r2.z; row[11] = r2.w;

            #pragma unroll
            for (int o = 0; o < 4; ++o) {
                const int kh = o + 6 - rr;
                if (kh < 0 || kh > 6) continue;
                #pragma unroll
                for (int kw = 0; kw < 7; ++kw)
                    #pragma unroll
                    for (int j = 0; j < 4; ++j)
                        pk_fma(acc[o][j], kv[kh & 3][kw], row[j + 6 - kw]);
            }
        }
        #pragma unroll
        for (int o = 0; o < 4; ++o)
            #pragma unroll
            for (int j = 0; j < 4; ++j) pk_add(tot[o][j], acc[o][j]);
    }

    _Float16* ob = out + (long long)b * 32 * PLANE + (long long)t * PLANE;
    #pragma unroll
    for (int o = 0; o < 4; ++o) {
        #pragma unroll
        for (int j = 0; j < 4; ++j) {
            _Float16* dst = ob + (((h0 + 4 * iq + o) * 64 + w0 + wq * 4 + j) * 64 + c0 + 2 * p);
            *reinterpret_cast<uint*>(dst) = tot[o][j];
        }
    }
}

// ---------------- minGRU scan over T (f32 math, f16 I/O) ----------------
__global__ __launch_bounds__(256) void scan_kernel(
    const __half2* __restrict__ gs, const __half2* __restrict__ hs, __half2* __restrict__ hout)
{
    const int tid = blockIdx.x * 256 + threadIdx.x;    // 0..262143 half2 lanes
    const int b = tid >> 17;
    const int q = tid & 131071;
    const long long bb = (long long)b * 32 * 131072 + q;
    float h0 = 0.f, h1 = 0.f;
    for (int t = 0; t < 32; ++t) {
        const long long a = bb + (long long)t * 131072;
        const float2 g  = __half22float2(gs[a]);
        const float2 hv = __half22float2(hs[a]);
        const float z0 = 1.f / (1.f + __expf(-g.x));
        const float z1 = 1.f / (1.f + __expf(-g.y));
        h0 = fmaf(1.f - z0, h0, z0 * fmaf(hv.x, hv.x, 1e-6f));
        h1 = fmaf(1.f - z1, h1, z1 * fmaf(hv.y, hv.y, 1e-6f));
        hout[a] = __floats2half2_rn(h0, h1);
    }
}

// ---------------- output GEMM (MFMA f16, f32 out) ----------------
__global__ __launch_bounds__(256) void outgemm_kernel(
    const _Float16* __restrict__ hin, const float* __restrict__ w,
    const float* __restrict__ bias, float* __restrict__ out)
{
    __shared__ __align__(16) _Float16 sX[128 * 64];
    __shared__ __align__(16) _Float16 sWT[64 * 64];
    const int tid = threadIdx.x;
    const long long row0 = (long long)blockIdx.x * 128;

    #pragma unroll
    for (int kci = 0; kci < 4; ++kci) {
        const int chunk = tid + kci * 256;
        const int r = chunk >> 3, q = chunk & 7;
        const f16x8 hv = *reinterpret_cast<const f16x8*>(hin + (row0 + r) * 64 + q * 8);
        *reinterpret_cast<f16x8*>(&sX[r * 64 + ((q ^ (r & 7)) * 8)]) = hv;
    }
    {
        const int d = tid & 63;
        const int cb = (tid >> 6) * 16;
        #pragma unroll
        for (int i = 0; i < 16; ++i) {
            const int c = cb + i;
            sWT[d * 64 + (((c >> 3) ^ (d & 7)) * 8) + (c & 7)] = (_Float16)w[c * 64 + d];
        }
    }
    __syncthreads();

    const int wv = tid >> 6, lm = tid & 15, lg = (tid & 63) >> 4;
    f16x8 bf[4][2];
    #pragma unroll
    for (int nt = 0; nt < 4; ++nt) {
        const int d = nt * 16 + lm;
        #pragma unroll
        for (int s = 0; s < 2; ++s)
            bf[nt][s] = *reinterpret_cast<const f16x8*>(&sWT[d * 64 + (((s * 4 + lg) ^ (d & 7)) * 8)]);
    }
    f32x4 acc[2][4];
    #pragma unroll
    for (int mt = 0; mt < 2; ++mt)
        #pragma unroll
        for (int nt = 0; nt < 4; ++nt)
            acc[mt][nt] = (f32x4){0.f, 0.f, 0.f, 0.f};

    #pragma unroll
    for (int mt = 0; mt < 2; ++mt) {
        const int r = wv * 32 + mt * 16 + lm;
        const f16x8 a0 = *reinterpret_cast<const f16x8*>(&sX[r * 64 + ((lg ^ (r & 7)) * 8)]);
        const f16x8 a1 = *reinterpret_cast<const f16x8*>(&sX[r * 64 + (((4 + lg) ^ (r & 7)) * 8)]);
        #pragma unroll
        for (int nt = 0; nt < 4; ++nt) {
            acc[mt][nt] = __builtin_amdgcn_mfma_f32_16x16x32_f16(a0, bf[nt][0], acc[mt][nt], 0, 0, 0);
            acc[mt][nt] = __builtin_amdgcn_mfma_f32_16x16x32_f16(a1, bf[nt][1], acc[mt][nt], 0, 0, 0);
        }
    }
    #pragma unroll
    for (int nt = 0; nt < 4; ++nt) {
        const int col = nt * 16 + lm;
        const float bv = bias[col];
        #pragma unroll
        for (int mt = 0; mt < 2; ++mt) {
            const long long rb = row0 + wv * 32 + mt * 16 + lg * 4;
            #pragma unroll
            for (int i = 0; i < 4; ++i)
                out[(rb + i) * 64 + col] = acc[mt][nt][i] + bv;
        }
    }
}

extern "C" void kernel_launch(void* const* d_in, const int* in_sizes, int n_in,
                              void* d_out, int out_size, void* d_ws, size_t ws_size,
                              hipStream_t stream)
{
    const float* x  = (const float*)d_in[0];
    const float* gw = (const float*)d_in[1];
    const float* gb = (const float*)d_in[2];
    const float* hw = (const float*)d_in[3];
    const float* hb = (const float*)d_in[4];
    const float* gk = (const float*)d_in[5];
    const float* hk = (const float*)d_in[6];
    const float* ow = (const float*)d_in[7];
    const float* ob = (const float*)d_in[8];

    _Float16* W1 = (_Float16*)d_ws;          // 33.5 MB each
    _Float16* W2 = W1 + NELEM;
    _Float16* W3 = W2 + NELEM;

    // 1) proj: x -> W1 (gate_proj f16), W2 (hidden_proj f16)
    proj2_kernel<<<2048, 256, 0, stream>>>(x, gw, gb, hw, hb, W1, W2);
    // 2+3) both convs in one launch: W1 -> W3 (gate), W2 -> d_ws reuse... W2 -> W1? No:
    //      gate conv reads W1 writes W3; hidden conv reads W2 writes... must not clobber W1
    //      while gate conv still reads it -> give hidden conv its own target: reuse d_out?
    //      d_out is f32 (67MB) - safe scratch: hidden_spatial f16 fits in first half.
    conv3d_dual_kernel<<<8192, 128, 0, stream>>>(W1, gk, W3, W2, hk, (_Float16*)d_out);
    // 4) scan: (W3 gate, d_out hidden) -> W2
    scan_kernel<<<1024, 256, 0, stream>>>((const __half2*)W3, (const __half2*)d_out, (__half2*)W2);
    // 5) out GEMM: W2 -> d_out (f32, overwrites scratch)
    outgemm_kernel<<<2048, 256, 0, stream>>>(W2, ow, ob, (float*)d_out);
}